// Round 1
// baseline (337.414 us; speedup 1.0000x reference)
//
#include <hip/hip_runtime.h>

#define INSZ   2048
#define NH1    256
#define NH2    64
#define NB     8
#define BATCH  16384

#define TS        64                 // rows per block-tile
#define MAXTILES  (BATCH / TS)       // 256 (worst case: all samples in one bucket)
#define GRIDX     (NB * MAXTILES)    // 2048, bkt = blockIdx & 7 -> XCD pin heuristic

// W1f: [bkt][kb(64)][cb(16)][lane(64)][8] bf16
#define W1F_U4   (NB * 64 * 16 * 64)        // 524288 uint4
#define W2F_U4   (NB * 8 * 4 * 64)          // 16384 uint4

// ws layout (bytes)
#define META_OFF  0                  // 32 ints: cnt[8], off[8], cursor[8]
#define ORDER_OFF 1024               // 16384 ints
#define W1F_OFF   (1024 + BATCH * 4)            // 66560
#define W2F_OFF   (W1F_OFF + W1F_U4 * 16)       // 8,455,168
#define WS_NEED   (W2F_OFF + W2F_U4 * 16)       // 8,717,312

typedef float f4  __attribute__((ext_vector_type(4)));
typedef float f32x4 __attribute__((ext_vector_type(4)));
typedef short bf16x8 __attribute__((ext_vector_type(8)));

__device__ __forceinline__ unsigned short f2bf(float f) {
    unsigned u = __float_as_uint(f);
    u += 0x7fffu + ((u >> 16) & 1u);   // RNE
    return (unsigned short)(u >> 16);
}
__device__ __forceinline__ float clamp01(float v) { return fminf(fmaxf(v, 0.0f), 1.0f); }
__device__ __forceinline__ unsigned pack2(float a, float b) {
    return (unsigned)f2bf(a) | ((unsigned)f2bf(b) << 16);
}

// ============================ pre-pass kernels ============================

__global__ void k_countscan(const int* __restrict__ idx, int* __restrict__ meta) {
    __shared__ int scnt[NB];
    int t = threadIdx.x;
    if (t < NB) scnt[t] = 0;
    __syncthreads();
    int local[NB];
#pragma unroll
    for (int bb = 0; bb < NB; bb++) local[bb] = 0;
    for (int i = t; i < BATCH; i += 1024) {
        int b = idx[i];
#pragma unroll
        for (int bb = 0; bb < NB; bb++) local[bb] += (b == bb) ? 1 : 0;
    }
#pragma unroll
    for (int bb = 0; bb < NB; bb++) {
        int v = local[bb];
        v += __shfl_xor(v, 1);  v += __shfl_xor(v, 2);  v += __shfl_xor(v, 4);
        v += __shfl_xor(v, 8);  v += __shfl_xor(v, 16); v += __shfl_xor(v, 32);
        if ((t & 63) == 0) atomicAdd(&scnt[bb], v);
    }
    __syncthreads();
    if (t == 0) {
        int run = 0;
        for (int b = 0; b < NB; b++) {
            int c = scnt[b];
            meta[b]      = c;
            meta[8 + b]  = run;
            meta[16 + b] = run;   // scatter cursor
            run += c;
        }
    }
}

__global__ void k_scatter(const int* __restrict__ idx, int* __restrict__ meta,
                          int* __restrict__ order) {
    __shared__ int wcnt[16][NB];
    __shared__ int sbase[NB];
    int t = threadIdx.x;
    int i = blockIdx.x * 1024 + t;
    int b = idx[i];
    int wv = t >> 6, lane = t & 63;
    unsigned long long mymask = 0;
#pragma unroll
    for (int bb = 0; bb < NB; bb++) {
        unsigned long long m = __ballot(b == bb);
        if (b == bb) mymask = m;
        if (lane == bb) wcnt[wv][bb] = (int)__popcll(m);
    }
    int myrank = (int)__popcll(mymask & ((1ull << lane) - 1ull));
    __syncthreads();
    if (t < NB) {
        int sum = 0;
        for (int w2 = 0; w2 < 16; w2++) { int c = wcnt[w2][t]; wcnt[w2][t] = sum; sum += c; }
        sbase[t] = atomicAdd(&meta[16 + t], sum);
    }
    __syncthreads();
    order[sbase[b] + wcnt[wv][b] + myrank] = i;
}

// pack W1/W2 into per-lane MFMA B-fragment order (bf16)
__global__ void k_pack(const float* __restrict__ W1, const float* __restrict__ W2,
                       uint4* __restrict__ W1f, uint4* __restrict__ W2f) {
    int u = blockIdx.x * 256 + threadIdx.x;
    if (u < W1F_U4) {
        int lane = u & 63, cb = (u >> 6) & 15, kb = (u >> 10) & 63, bkt = u >> 16;
        int l15 = lane & 15, quad = lane >> 4;
        const float* p = W1 + (size_t)(bkt * NH1 + cb * 16 + l15) * INSZ + kb * 32 + quad * 8;
        f4 lo = *(const f4*)p, hi = *(const f4*)(p + 4);
        uint4 o;
        o.x = pack2(lo[0], lo[1]); o.y = pack2(lo[2], lo[3]);
        o.z = pack2(hi[0], hi[1]); o.w = pack2(hi[2], hi[3]);
        W1f[u] = o;
    } else {
        int v = u - W1F_U4;
        if (v >= W2F_U4) return;
        int lane = v & 63, cg2 = (v >> 6) & 3, kb2 = (v >> 8) & 7, bkt = v >> 11;
        int l15 = lane & 15, quad = lane >> 4;
        const float* p = W2 + (size_t)(bkt * NH2 + cg2 * 16 + l15) * NH1 + kb2 * 32 + quad * 8;
        f4 lo = *(const f4*)p, hi = *(const f4*)(p + 4);
        uint4 o;
        o.x = pack2(lo[0], lo[1]); o.y = pack2(lo[2], lo[3]);
        o.z = pack2(hi[0], hi[1]); o.w = pack2(hi[2], hi[3]);
        W2f[v] = o;
    }
}

// ============================ main fused kernel ============================
// v7: wave w owns cols w*32..w*32+31 (cb = 2w,2w+1) over all 64 rows
// (4 A-frags x 2 B-frags = 8 MFMA/step). B-fragments are wave-private ->
// W1 loads go straight global(L2)->VGPR with a 1-step register double-buffer;
// no sW LDS, no global_load_lds, no vmcnt(0) drain. x is reg-staged 1.5 steps
// ahead (issue x(k+2) at step k, ds_write x(k+1) at step k bottom). Barriers
// are raw s_barrier preceded by lgkmcnt(0) only: prefetches stay in flight
// across K-steps. Active tiles are spread over the dispatch range so ~1
// active block lands per CU regardless of scheduler slot-fill policy.

__global__ __launch_bounds__(512, 2) void fused_v7(
    const float* __restrict__ x, const int* __restrict__ meta,
    const int* __restrict__ order,
    const short* __restrict__ W1f, const short* __restrict__ W2f,
    const float* __restrict__ b1, const float* __restrict__ b2,
    const float* __restrict__ W3, const float* __restrict__ b3,
    float* __restrict__ out)
{
    const int bkt  = blockIdx.x & 7;
    const int u    = blockIdx.x >> 3;
    const int tile = ((u & 7) << 5) | (u >> 3);   // bijective 0..255, spreads actives
    const int cnt  = meta[bkt];
    const int base = tile * TS;
    if (base >= cnt) return;
    const int off = meta[8 + bkt];

    __shared__ short sX[2][TS * 40];     // 2 x 5 KB   x k-step (bf16, stride 40)
    __shared__ short sh1[TS * 264];      // 33.8 KB    h1 (bf16)
    __shared__ float sPart[2][TS];

    const int t = threadIdx.x;
    const int lane = t & 63, w = t >> 6;
    const int l15 = lane & 15, quad = lane >> 4;

    // x staging: thread t -> row t>>3, 4 floats at (t&7)*4
    const int xr = t >> 3, kq = t & 7;
    int ir = base + xr; if (ir > cnt - 1) ir = cnt - 1;
    const float* xtp = x + (size_t)order[off + ir] * INSZ + kq * 4;
    const int sxo = xr * 40 + kq * 4;

    // per-wave W1 fragment pointer: frag (kb, cb=2w+j) at kb*8192 + j*512 (+lane*8)
    const short* wp = W1f + ((size_t)bkt << 19) + (size_t)(2 * w) * 512 + lane * 8;

    f32x4 acc[4][2];
#pragma unroll
    for (int f = 0; f < 4; f++)
#pragma unroll
        for (int j = 0; j < 2; j++) acc[f][j] = (f32x4)0.0f;

    bf16x8 wA0, wA1, wB0, wB1;   // W register double-buffer (set A = even steps)
    f4 xs0, xs1;                 // x register double-buffer (set parity = step parity)

    // ---- prologue: W(0) -> set A, x(0) -> LDS buf 0, x(1) -> xs1 ----
    wA0 = *(const bf16x8*)(wp);
    wA1 = *(const bf16x8*)(wp + 512);
    {
        f4 x0 = *(const f4*)xtp;
        xs1 = *(const f4*)(xtp + 32);
        uint2 pk; pk.x = pack2(x0[0], x0[1]); pk.y = pack2(x0[2], x0[3]);
        *(uint2*)&sX[0][sxo] = pk;
    }

    // One raw barrier per K-step; lgkmcnt(0) covers the ds_write of x(k) from
    // all waves. vmcnt is NEVER forced to 0: W(k+1)/x(k+2) stay in flight and
    // the compiler inserts counted waits at their uses one step later.
#define L1_STEP(KB, P, WU0, WU1, WL0, WL1, XW, XL)                                      \
    {                                                                                   \
        asm volatile("s_waitcnt lgkmcnt(0)" ::: "memory");                              \
        __builtin_amdgcn_s_barrier();                                                   \
        asm volatile("" ::: "memory");                                                  \
        if ((KB) < 63) {                                                                \
            WL0 = *(const bf16x8*)(wp + (size_t)((KB) + 1) * 8192);                     \
            WL1 = *(const bf16x8*)(wp + (size_t)((KB) + 1) * 8192 + 512);               \
        }                                                                               \
        if ((KB) < 62) XL = *(const f4*)(xtp + ((KB) + 2) * 32);                        \
        bf16x8 a0 = *(const bf16x8*)&sX[P][(l15)      * 40 + quad * 8];                 \
        bf16x8 a1 = *(const bf16x8*)&sX[P][(16 + l15) * 40 + quad * 8];                 \
        bf16x8 a2 = *(const bf16x8*)&sX[P][(32 + l15) * 40 + quad * 8];                 \
        bf16x8 a3 = *(const bf16x8*)&sX[P][(48 + l15) * 40 + quad * 8];                 \
        acc[0][0] = __builtin_amdgcn_mfma_f32_16x16x32_bf16(a0, WU0, acc[0][0], 0,0,0); \
        acc[0][1] = __builtin_amdgcn_mfma_f32_16x16x32_bf16(a0, WU1, acc[0][1], 0,0,0); \
        acc[1][0] = __builtin_amdgcn_mfma_f32_16x16x32_bf16(a1, WU0, acc[1][0], 0,0,0); \
        acc[1][1] = __builtin_amdgcn_mfma_f32_16x16x32_bf16(a1, WU1, acc[1][1], 0,0,0); \
        acc[2][0] = __builtin_amdgcn_mfma_f32_16x16x32_bf16(a2, WU0, acc[2][0], 0,0,0); \
        acc[2][1] = __builtin_amdgcn_mfma_f32_16x16x32_bf16(a2, WU1, acc[2][1], 0,0,0); \
        acc[3][0] = __builtin_amdgcn_mfma_f32_16x16x32_bf16(a3, WU0, acc[3][0], 0,0,0); \
        acc[3][1] = __builtin_amdgcn_mfma_f32_16x16x32_bf16(a3, WU1, acc[3][1], 0,0,0); \
        if ((KB) < 63) {                                                                \
            uint2 pk; pk.x = pack2(XW[0], XW[1]); pk.y = pack2(XW[2], XW[3]);           \
            *(uint2*)&sX[(P) ^ 1][sxo] = pk;                                            \
        }                                                                               \
    }

#pragma unroll 1
    for (int kb = 0; kb < 64; kb += 2) {
        L1_STEP(kb,     0, wA0, wA1, wB0, wB1, xs1, xs0)
        L1_STEP(kb + 1, 1, wB0, wB1, wA0, wA1, xs0, xs1)
    }
#undef L1_STEP

    // ---- layer-1 epilogue: bias + clip01 -> sh1 ----
#pragma unroll
    for (int j = 0; j < 2; j++) {
        int col = w * 32 + j * 16 + l15;
        float bias = b1[bkt * NH1 + col];
#pragma unroll
        for (int f = 0; f < 4; f++)
#pragma unroll
            for (int r = 0; r < 4; r++) {
                int row = f * 16 + quad * 4 + r;
                sh1[row * 264 + col] = (short)f2bf(clamp01(acc[f][j][r] + bias));
            }
    }
    __syncthreads();

    // ---- layer 2: wave w -> h2 rows (w&3)*16..+15, cols (w>>2)*32..+31 ----
    const int rw = w & 3, ch2 = w >> 2;
    f32x4 c2[2];
    c2[0] = (f32x4)0.0f; c2[1] = (f32x4)0.0f;
    const short* w2p = W2f + (size_t)bkt * 16384 + lane * 8;
#pragma unroll
    for (int kb2 = 0; kb2 < 8; kb2++) {
        bf16x8 a2 = *(const bf16x8*)&sh1[(rw * 16 + l15) * 264 + kb2 * 32 + quad * 8];
#pragma unroll
        for (int j = 0; j < 2; j++) {
            bf16x8 bw = *(const bf16x8*)(w2p + (kb2 * 4 + ch2 * 2 + j) * 512);
            c2[j] = __builtin_amdgcn_mfma_f32_16x16x32_bf16(a2, bw, c2[j], 0, 0, 0);
        }
    }

    // ---- layer-2 epilogue + layer-3 partial dot ----
    float s[4] = {0, 0, 0, 0};
#pragma unroll
    for (int j = 0; j < 2; j++) {
        int n2 = (ch2 * 2 + j) * 16 + l15;
        float bias2 = b2[bkt * NH2 + n2];
        float w3v   = W3[bkt * NH2 + n2];
#pragma unroll
        for (int r = 0; r < 4; r++)
            s[r] += clamp01(c2[j][r] + bias2) * w3v;
    }
#pragma unroll
    for (int r = 0; r < 4; r++) {
        float pp = s[r];
        pp += __shfl_xor(pp, 1); pp += __shfl_xor(pp, 2);
        pp += __shfl_xor(pp, 4); pp += __shfl_xor(pp, 8);
        if (l15 == 0) sPart[ch2][rw * 16 + quad * 4 + r] = pp;
    }
    __syncthreads();
    if (t < TS && base + t < cnt)
        out[order[off + base + t]] = sPart[0][t] + sPart[1][t] + b3[bkt];
}

// ============================ naive fallback ============================

__global__ void naive_mlp(const float* __restrict__ x, const int* __restrict__ idx,
                          const float* __restrict__ W1, const float* __restrict__ b1,
                          const float* __restrict__ W2, const float* __restrict__ b2,
                          const float* __restrict__ W3, const float* __restrict__ b3,
                          float* __restrict__ out)
{
    int i = blockIdx.x;
    int b = idx[i];
    __shared__ float sx[INSZ];
    __shared__ float sh1n[NH1];
    __shared__ float sh2n[NH2];
    for (int t = threadIdx.x; t < INSZ; t += 256) sx[t] = x[(size_t)i * INSZ + t];
    __syncthreads();
    int j = threadIdx.x;
    {
        const float* wr = W1 + (size_t)(b * NH1 + j) * INSZ;
        float acc = b1[b * NH1 + j];
        for (int k = 0; k < INSZ; k++) acc += sx[k] * wr[k];
        sh1n[j] = fminf(fmaxf(acc, 0.f), 1.f);
    }
    __syncthreads();
    if (j < NH2) {
        const float* wr = W2 + (size_t)(b * NH2 + j) * NH1;
        float acc = b2[b * NH2 + j];
        for (int k = 0; k < NH1; k++) acc += sh1n[k] * wr[k];
        sh2n[j] = fminf(fmaxf(acc, 0.f), 1.f);
    }
    __syncthreads();
    if (j == 0) {
        float acc = b3[b];
        for (int k = 0; k < NH2; k++) acc += sh2n[k] * W3[b * NH2 + k];
        out[i] = acc;
    }
}

extern "C" void kernel_launch(void* const* d_in, const int* in_sizes, int n_in,
                              void* d_out, int out_size, void* d_ws, size_t ws_size,
                              hipStream_t stream) {
    const float* x  = (const float*)d_in[0];
    const int* bidx = (const int*)d_in[1];
    const float* W1 = (const float*)d_in[2];
    const float* b1 = (const float*)d_in[3];
    const float* W2 = (const float*)d_in[4];
    const float* b2 = (const float*)d_in[5];
    const float* W3 = (const float*)d_in[6];
    const float* b3 = (const float*)d_in[7];
    float* out = (float*)d_out;

    if (ws_size >= (size_t)WS_NEED) {
        char* ws = (char*)d_ws;
        int*   meta  = (int*)(ws + META_OFF);
        int*   order = (int*)(ws + ORDER_OFF);
        uint4* W1f   = (uint4*)(ws + W1F_OFF);
        uint4* W2f   = (uint4*)(ws + W2F_OFF);

        k_countscan<<<1, 1024, 0, stream>>>(bidx, meta);
        k_scatter<<<BATCH / 1024, 1024, 0, stream>>>(bidx, meta, order);
        k_pack<<<(W1F_U4 + W2F_U4) / 256, 256, 0, stream>>>(W1, W2, W1f, W2f);
        fused_v7<<<GRIDX, 512, 0, stream>>>(x, meta, order,
                                            (const short*)W1f, (const short*)W2f,
                                            b1, b2, W3, b3, out);
    } else {
        naive_mlp<<<BATCH, 256, 0, stream>>>(x, bidx, W1, b1, W2, b2, W3, b3, out);
    }
}

// Round 2
// 258.729 us; speedup vs baseline: 1.3041x; 1.3041x over previous
//
#include <hip/hip_runtime.h>

#define INSZ   2048
#define NH1    256
#define NH2    64
#define NB     8
#define BATCH  16384

#define TS        64                 // rows per block-tile
#define MAXTILES  (BATCH / TS)       // 256 (worst case: all samples in one bucket)
#define GRIDX     (NB * MAXTILES)    // 2048, bkt = blockIdx & 7 -> XCD pin heuristic

// W1f: [bkt][kb(64)][cb(16)][lane(64)][8] bf16
#define W1F_U4   (NB * 64 * 16 * 64)        // 524288 uint4
#define W2F_U4   (NB * 8 * 4 * 64)          // 16384 uint4

// ws layout (bytes)
#define META_OFF  0                  // 32 ints: cnt[8], off[8], cursor[8]
#define ORDER_OFF 1024               // 16384 ints
#define W1F_OFF   (1024 + BATCH * 4)            // 66560
#define W2F_OFF   (W1F_OFF + W1F_U4 * 16)       // 8,455,168
#define WS_NEED   (W2F_OFF + W2F_U4 * 16)       // 8,717,312

typedef float f4  __attribute__((ext_vector_type(4)));
typedef float f32x4 __attribute__((ext_vector_type(4)));
typedef short bf16x8 __attribute__((ext_vector_type(8)));

__device__ __forceinline__ unsigned short f2bf(float f) {
    unsigned u = __float_as_uint(f);
    u += 0x7fffu + ((u >> 16) & 1u);   // RNE
    return (unsigned short)(u >> 16);
}
__device__ __forceinline__ float clamp01(float v) { return fminf(fmaxf(v, 0.0f), 1.0f); }
__device__ __forceinline__ unsigned pack2(float a, float b) {
    return (unsigned)f2bf(a) | ((unsigned)f2bf(b) << 16);
}

// ============================ pre-pass kernels ============================

__global__ void k_countscan(const int* __restrict__ idx, int* __restrict__ meta) {
    __shared__ int scnt[NB];
    int t = threadIdx.x;
    if (t < NB) scnt[t] = 0;
    __syncthreads();
    int local[NB];
#pragma unroll
    for (int bb = 0; bb < NB; bb++) local[bb] = 0;
    for (int i = t; i < BATCH; i += 1024) {
        int b = idx[i];
#pragma unroll
        for (int bb = 0; bb < NB; bb++) local[bb] += (b == bb) ? 1 : 0;
    }
#pragma unroll
    for (int bb = 0; bb < NB; bb++) {
        int v = local[bb];
        v += __shfl_xor(v, 1);  v += __shfl_xor(v, 2);  v += __shfl_xor(v, 4);
        v += __shfl_xor(v, 8);  v += __shfl_xor(v, 16); v += __shfl_xor(v, 32);
        if ((t & 63) == 0) atomicAdd(&scnt[bb], v);
    }
    __syncthreads();
    if (t == 0) {
        int run = 0;
        for (int b = 0; b < NB; b++) {
            int c = scnt[b];
            meta[b]      = c;
            meta[8 + b]  = run;
            meta[16 + b] = run;   // scatter cursor
            run += c;
        }
    }
}

__global__ void k_scatter(const int* __restrict__ idx, int* __restrict__ meta,
                          int* __restrict__ order) {
    __shared__ int wcnt[16][NB];
    __shared__ int sbase[NB];
    int t = threadIdx.x;
    int i = blockIdx.x * 1024 + t;
    int b = idx[i];
    int wv = t >> 6, lane = t & 63;
    unsigned long long mymask = 0;
#pragma unroll
    for (int bb = 0; bb < NB; bb++) {
        unsigned long long m = __ballot(b == bb);
        if (b == bb) mymask = m;
        if (lane == bb) wcnt[wv][bb] = (int)__popcll(m);
    }
    int myrank = (int)__popcll(mymask & ((1ull << lane) - 1ull));
    __syncthreads();
    if (t < NB) {
        int sum = 0;
        for (int w2 = 0; w2 < 16; w2++) { int c = wcnt[w2][t]; wcnt[w2][t] = sum; sum += c; }
        sbase[t] = atomicAdd(&meta[16 + t], sum);
    }
    __syncthreads();
    order[sbase[b] + wcnt[wv][b] + myrank] = i;
}

// pack W1/W2 into per-lane MFMA B-fragment order (bf16)
__global__ void k_pack(const float* __restrict__ W1, const float* __restrict__ W2,
                       uint4* __restrict__ W1f, uint4* __restrict__ W2f) {
    int u = blockIdx.x * 256 + threadIdx.x;
    if (u < W1F_U4) {
        int lane = u & 63, cb = (u >> 6) & 15, kb = (u >> 10) & 63, bkt = u >> 16;
        int l15 = lane & 15, quad = lane >> 4;
        const float* p = W1 + (size_t)(bkt * NH1 + cb * 16 + l15) * INSZ + kb * 32 + quad * 8;
        f4 lo = *(const f4*)p, hi = *(const f4*)(p + 4);
        uint4 o;
        o.x = pack2(lo[0], lo[1]); o.y = pack2(lo[2], lo[3]);
        o.z = pack2(hi[0], hi[1]); o.w = pack2(hi[2], hi[3]);
        W1f[u] = o;
    } else {
        int v = u - W1F_U4;
        if (v >= W2F_U4) return;
        int lane = v & 63, cg2 = (v >> 6) & 3, kb2 = (v >> 8) & 7, bkt = v >> 11;
        int l15 = lane & 15, quad = lane >> 4;
        const float* p = W2 + (size_t)(bkt * NH2 + cg2 * 16 + l15) * NH1 + kb2 * 32 + quad * 8;
        f4 lo = *(const f4*)p, hi = *(const f4*)(p + 4);
        uint4 o;
        o.x = pack2(lo[0], lo[1]); o.y = pack2(lo[2], lo[3]);
        o.z = pack2(hi[0], hi[1]); o.w = pack2(hi[2], hi[3]);
        W2f[v] = o;
    }
}

// ============================ main fused kernel ============================
// v8 = v7 structure with two fixes:
//  (1) identity tile mapping restored (v7's "spread" put all 256 active
//      blocks on ~32 CUs under round-robin XCD dispatch; identity gives
//      exactly 1 active block per CU, XCD-striped by bkt).
//  (2) deep register pipeline with counted waits: x prefetched 4 K-steps
//      ahead (4 rotating f4 regs, unroll-4), W1 fragments reloaded into the
//      just-freed register set at step bottom (-> ~2 steps of age at use).
//      Barriers are raw s_barrier + lgkmcnt(0) only; vmcnt is never forced
//      to 0 in the loop, so the compiler emits counted vmcnt(N) at first
//      use and global loads stay in flight across barriers.

__global__ __launch_bounds__(512, 2) void fused_v8(
    const float* __restrict__ x, const int* __restrict__ meta,
    const int* __restrict__ order,
    const short* __restrict__ W1f, const short* __restrict__ W2f,
    const float* __restrict__ b1, const float* __restrict__ b2,
    const float* __restrict__ W3, const float* __restrict__ b3,
    float* __restrict__ out)
{
    const int bkt  = blockIdx.x & 7;
    const int tile = blockIdx.x >> 3;     // identity: actives = first ~256 blocks
    const int cnt  = meta[bkt];
    const int base = tile * TS;
    if (base >= cnt) return;
    const int off = meta[8 + bkt];

    __shared__ short sX[2][TS * 40];     // 2 x 5 KB   x k-step (bf16, stride 40)
    __shared__ short sh1[TS * 264];      // 33.8 KB    h1 (bf16)
    __shared__ float sPart[2][TS];

    const int t = threadIdx.x;
    const int lane = t & 63, w = t >> 6;
    const int l15 = lane & 15, quad = lane >> 4;

    // x staging: thread t -> row t>>3, 4 floats at (t&7)*4
    const int xr = t >> 3, kq = t & 7;
    int ir = base + xr; if (ir > cnt - 1) ir = cnt - 1;
    const float* xtp = x + (size_t)order[off + ir] * INSZ + kq * 4;
    const int sxo = xr * 40 + kq * 4;

    // per-wave W1 fragment pointer: frag (kb, cb=2w+j) at kb*8192 + j*512 (+lane*8)
    const short* wp = W1f + ((size_t)bkt << 19) + (size_t)(2 * w) * 512 + lane * 8;

    f32x4 acc[4][2];
#pragma unroll
    for (int f = 0; f < 4; f++)
#pragma unroll
        for (int j = 0; j < 2; j++) acc[f][j] = (f32x4)0.0f;

    bf16x8 wA0, wA1, wB0, wB1;   // W reg double-buffer: set = kb&1, reloaded at use-step
    f4 xs0, xs1, xs2, xs3;       // x pipeline: slot s holds x(m), m%4==s, depth 4

    // ---- prologue: W(0),W(1) -> regs; x(0) -> LDS buf0; x(1..3) -> slots ----
    wA0 = *(const bf16x8*)(wp);
    wA1 = *(const bf16x8*)(wp + 512);
    wB0 = *(const bf16x8*)(wp + 8192);
    wB1 = *(const bf16x8*)(wp + 8192 + 512);
    {
        f4 x0 = *(const f4*)xtp;
        xs1 = *(const f4*)(xtp + 32);
        xs2 = *(const f4*)(xtp + 64);
        xs3 = *(const f4*)(xtp + 96);
        uint2 pk; pk.x = pack2(x0[0], x0[1]); pk.y = pack2(x0[2], x0[3]);
        *(uint2*)&sX[0][sxo] = pk;
    }

    // Per step KB: [load x(KB+4) -> slot KB%4] | lgkm(0)+barrier |
    //   ds_read 4 A-frags | 8 MFMA on W(KB) | pack+ds_write x(KB+1) from
    //   slot (KB+1)%4 | [reload freed W set with W(KB+2)].
#define L1_STEP(KB, XL, XW, WU0, WU1)                                                   \
    {                                                                                   \
        if ((KB) < 60) XL = *(const f4*)(xtp + ((KB) + 4) * 32);                        \
        asm volatile("s_waitcnt lgkmcnt(0)" ::: "memory");                              \
        __builtin_amdgcn_s_barrier();                                                   \
        asm volatile("" ::: "memory");                                                  \
        const int P = (KB) & 1;                                                         \
        bf16x8 a0 = *(const bf16x8*)&sX[P][(l15)      * 40 + quad * 8];                 \
        bf16x8 a1 = *(const bf16x8*)&sX[P][(16 + l15) * 40 + quad * 8];                 \
        bf16x8 a2 = *(const bf16x8*)&sX[P][(32 + l15) * 40 + quad * 8];                 \
        bf16x8 a3 = *(const bf16x8*)&sX[P][(48 + l15) * 40 + quad * 8];                 \
        acc[0][0] = __builtin_amdgcn_mfma_f32_16x16x32_bf16(a0, WU0, acc[0][0], 0,0,0); \
        acc[0][1] = __builtin_amdgcn_mfma_f32_16x16x32_bf16(a0, WU1, acc[0][1], 0,0,0); \
        acc[1][0] = __builtin_amdgcn_mfma_f32_16x16x32_bf16(a1, WU0, acc[1][0], 0,0,0); \
        acc[1][1] = __builtin_amdgcn_mfma_f32_16x16x32_bf16(a1, WU1, acc[1][1], 0,0,0); \
        acc[2][0] = __builtin_amdgcn_mfma_f32_16x16x32_bf16(a2, WU0, acc[2][0], 0,0,0); \
        acc[2][1] = __builtin_amdgcn_mfma_f32_16x16x32_bf16(a2, WU1, acc[2][1], 0,0,0); \
        acc[3][0] = __builtin_amdgcn_mfma_f32_16x16x32_bf16(a3, WU0, acc[3][0], 0,0,0); \
        acc[3][1] = __builtin_amdgcn_mfma_f32_16x16x32_bf16(a3, WU1, acc[3][1], 0,0,0); \
        if ((KB) < 63) {                                                                \
            uint2 pk; pk.x = pack2(XW[0], XW[1]); pk.y = pack2(XW[2], XW[3]);           \
            *(uint2*)&sX[P ^ 1][sxo] = pk;                                              \
        }                                                                               \
        if ((KB) < 62) {                                                                \
            WU0 = *(const bf16x8*)(wp + (size_t)((KB) + 2) * 8192);                     \
            WU1 = *(const bf16x8*)(wp + (size_t)((KB) + 2) * 8192 + 512);               \
        }                                                                               \
    }

#pragma unroll 1
    for (int kb = 0; kb < 64; kb += 4) {
        L1_STEP(kb + 0, xs0, xs1, wA0, wA1)
        L1_STEP(kb + 1, xs1, xs2, wB0, wB1)
        L1_STEP(kb + 2, xs2, xs3, wA0, wA1)
        L1_STEP(kb + 3, xs3, xs0, wB0, wB1)
    }
#undef L1_STEP

    // ---- layer-1 epilogue: bias + clip01 -> sh1 ----
#pragma unroll
    for (int j = 0; j < 2; j++) {
        int col = w * 32 + j * 16 + l15;
        float bias = b1[bkt * NH1 + col];
#pragma unroll
        for (int f = 0; f < 4; f++)
#pragma unroll
            for (int r = 0; r < 4; r++) {
                int row = f * 16 + quad * 4 + r;
                sh1[row * 264 + col] = (short)f2bf(clamp01(acc[f][j][r] + bias));
            }
    }
    __syncthreads();

    // ---- layer 2: wave w -> h2 rows (w&3)*16..+15, cols (w>>2)*32..+31 ----
    const int rw = w & 3, ch2 = w >> 2;
    f32x4 c2[2];
    c2[0] = (f32x4)0.0f; c2[1] = (f32x4)0.0f;
    const short* w2p = W2f + (size_t)bkt * 16384 + lane * 8;
#pragma unroll
    for (int kb2 = 0; kb2 < 8; kb2++) {
        bf16x8 a2 = *(const bf16x8*)&sh1[(rw * 16 + l15) * 264 + kb2 * 32 + quad * 8];
#pragma unroll
        for (int j = 0; j < 2; j++) {
            bf16x8 bw = *(const bf16x8*)(w2p + (kb2 * 4 + ch2 * 2 + j) * 512);
            c2[j] = __builtin_amdgcn_mfma_f32_16x16x32_bf16(a2, bw, c2[j], 0, 0, 0);
        }
    }

    // ---- layer-2 epilogue + layer-3 partial dot ----
    float s[4] = {0, 0, 0, 0};
#pragma unroll
    for (int j = 0; j < 2; j++) {
        int n2 = (ch2 * 2 + j) * 16 + l15;
        float bias2 = b2[bkt * NH2 + n2];
        float w3v   = W3[bkt * NH2 + n2];
#pragma unroll
        for (int r = 0; r < 4; r++)
            s[r] += clamp01(c2[j][r] + bias2) * w3v;
    }
#pragma unroll
    for (int r = 0; r < 4; r++) {
        float pp = s[r];
        pp += __shfl_xor(pp, 1); pp += __shfl_xor(pp, 2);
        pp += __shfl_xor(pp, 4); pp += __shfl_xor(pp, 8);
        if (l15 == 0) sPart[ch2][rw * 16 + quad * 4 + r] = pp;
    }
    __syncthreads();
    if (t < TS && base + t < cnt)
        out[order[off + base + t]] = sPart[0][t] + sPart[1][t] + b3[bkt];
}

// ============================ naive fallback ============================

__global__ void naive_mlp(const float* __restrict__ x, const int* __restrict__ idx,
                          const float* __restrict__ W1, const float* __restrict__ b1,
                          const float* __restrict__ W2, const float* __restrict__ b2,
                          const float* __restrict__ W3, const float* __restrict__ b3,
                          float* __restrict__ out)
{
    int i = blockIdx.x;
    int b = idx[i];
    __shared__ float sx[INSZ];
    __shared__ float sh1n[NH1];
    __shared__ float sh2n[NH2];
    for (int t = threadIdx.x; t < INSZ; t += 256) sx[t] = x[(size_t)i * INSZ + t];
    __syncthreads();
    int j = threadIdx.x;
    {
        const float* wr = W1 + (size_t)(b * NH1 + j) * INSZ;
        float acc = b1[b * NH1 + j];
        for (int k = 0; k < INSZ; k++) acc += sx[k] * wr[k];
        sh1n[j] = fminf(fmaxf(acc, 0.f), 1.f);
    }
    __syncthreads();
    if (j < NH2) {
        const float* wr = W2 + (size_t)(b * NH2 + j) * NH1;
        float acc = b2[b * NH2 + j];
        for (int k = 0; k < NH1; k++) acc += sh1n[k] * wr[k];
        sh2n[j] = fminf(fmaxf(acc, 0.f), 1.f);
    }
    __syncthreads();
    if (j == 0) {
        float acc = b3[b];
        for (int k = 0; k < NH2; k++) acc += sh2n[k] * W3[b * NH2 + k];
        out[i] = acc;
    }
}

extern "C" void kernel_launch(void* const* d_in, const int* in_sizes, int n_in,
                              void* d_out, int out_size, void* d_ws, size_t ws_size,
                              hipStream_t stream) {
    const float* x  = (const float*)d_in[0];
    const int* bidx = (const int*)d_in[1];
    const float* W1 = (const float*)d_in[2];
    const float* b1 = (const float*)d_in[3];
    const float* W2 = (const float*)d_in[4];
    const float* b2 = (const float*)d_in[5];
    const float* W3 = (const float*)d_in[6];
    const float* b3 = (const float*)d_in[7];
    float* out = (float*)d_out;

    if (ws_size >= (size_t)WS_NEED) {
        char* ws = (char*)d_ws;
        int*   meta  = (int*)(ws + META_OFF);
        int*   order = (int*)(ws + ORDER_OFF);
        uint4* W1f   = (uint4*)(ws + W1F_OFF);
        uint4* W2f   = (uint4*)(ws + W2F_OFF);

        k_countscan<<<1, 1024, 0, stream>>>(bidx, meta);
        k_scatter<<<BATCH / 1024, 1024, 0, stream>>>(bidx, meta, order);
        k_pack<<<(W1F_U4 + W2F_U4) / 256, 256, 0, stream>>>(W1, W2, W1f, W2f);
        fused_v8<<<GRIDX, 512, 0, stream>>>(x, meta, order,
                                            (const short*)W1f, (const short*)W2f,
                                            b1, b2, W3, b3, out);
    } else {
        naive_mlp<<<BATCH, 256, 0, stream>>>(x, bidx, W1, b1, W2, b2, W3, b3, out);
    }
}